// Round 5
// baseline (66.166 us; speedup 1.0000x reference)
//
#include <hip/hip_runtime.h>
#include <hip/hip_bf16.h>
#include <math.h>

#define BB  4
#define TT  8192
#define DD  64
#define PP  8
#define CC  32            // chunk length along t
#define NCH (TT/CC)       // 256 chunks
#define SSTR 65           // pass1 SH stride (floats): conflict-free rows+cols, scalar access only

#define EPSV 1e-3f
#define KPI4 0.78539816339744830962f

typedef __attribute__((ext_vector_type(8))) short short8;   // 8 bf16
typedef __attribute__((ext_vector_type(4))) float f32x4;

__device__ __forceinline__ float bf2f(unsigned short h) {
  return __uint_as_float(((unsigned)h) << 16);
}
__device__ __forceinline__ unsigned short f2bf(float f) {   // RNE
  unsigned u = __float_as_uint(f);
  u += 0x7fffu + ((u >> 16) & 1u);
  return (unsigned short)(u >> 16);
}
__device__ __forceinline__ float fast_tanh(float x) {
  float e = __expf(2.f * x);
  return 1.f - 2.f * __builtin_amdgcn_rcpf(e + 1.f);
}
__device__ __forceinline__ float rlane(float v, int lane) {
  return __uint_as_float(__builtin_amdgcn_readlane(__float_as_uint(v), lane));
}

// ---- Pass 1: per-(b,chunk) aggregates; blocks 0..7 also build WvT hi/lo ----
__global__ __launch_bounds__(256) void k_pass1(const float* __restrict__ q,
                                               const float* __restrict__ Wk,
                                               const float* __restrict__ Wv,
                                               float* __restrict__ aggC,
                                               float* __restrict__ aggS,
                                               unsigned short* __restrict__ WvTh,
                                               unsigned short* __restrict__ WvTl) {
  const int blk = blockIdx.x;
  const int c = blk & (NCH - 1);
  const int b = blk >> 8;

  __shared__ float SH[64 * SSTR];           // Q cols (32 rows used); reused for Wv

  const int tid = threadIdx.x;
  const int w = tid >> 6, l = tid & 63;
  const int sub = l >> 5, tA = l & 31;
  const int pA = w + 4 * sub;

  const float* qb = q + ((size_t)b * TT + (size_t)c * CC) * DD;
  for (int g = tid; g < CC * DD; g += 256) SH[(g >> 6) * SSTR + (g & 63)] = qb[g];

  // k-dot from GLOBAL (L1-hot) + trig; wave w holds p=w (lanes 0-31), p=w+4 (32-63)
  float ckR, skR;
  {
    const float4* qr = (const float4*)(qb + tA * DD);
    const float4* wr = (const float4*)(Wk + pA * DD);
    float dk = 0.f;
#pragma unroll
    for (int j = 0; j < 16; ++j) {
      float4 qv = qr[j], wv = wr[j];
      dk = fmaf(qv.x, wv.x, dk); dk = fmaf(qv.y, wv.y, dk);
      dk = fmaf(qv.z, wv.z, dk); dk = fmaf(qv.w, wv.w, dk);
    }
    float ang = fast_tanh(dk) * KPI4;
    ckR = __cosf(ang); skR = __sinf(ang);
    float rc = ckR, rs = skR;
#pragma unroll
    for (int d = 16; d >= 1; d >>= 1) {
      rc += __shfl_xor(rc, d, 32);
      rs += __shfl_xor(rs, d, 32);
    }
    if (tA == 0) {
      float* s = aggS + ((size_t)(b * PP + pA) * NCH + c) * 2;
      *(float2*)s = make_float2(rc, rs);
    }
  }
  __syncthreads();

  // d-space aggregates: wave w covers p=w and p=w+4; thread owns i=l.
  {
    float qcol[CC];
#pragma unroll
    for (int t = 0; t < CC; ++t) qcol[t] = SH[t * SSTR + l];
    float c0 = 0, s0 = 0, c1 = 0, s1 = 0;
#pragma unroll
    for (int t = 0; t < CC; ++t) {
      float a0 = rlane(ckR, t), b0 = rlane(skR, t);
      float a1 = rlane(ckR, t + 32), b1 = rlane(skR, t + 32);
      c0 = fmaf(a0, qcol[t], c0); s0 = fmaf(b0, qcol[t], s0);
      c1 = fmaf(a1, qcol[t], c1); s1 = fmaf(b1, qcol[t], s1);
    }
    float* a0p = aggC + ((size_t)(b * PP + w) * NCH + c) * 128;
    float* a1p = aggC + ((size_t)(b * PP + w + 4) * NCH + c) * 128;
    a0p[l] = c0; a0p[64 + l] = s0;
    a1p[l] = c1; a1p[64 + l] = s1;
  }

  // Wv transpose + double-bf16 split: blocks 0..7, one 64-k tile each.
  if (blk < 8) {
    __syncthreads();
    const int k0 = blk * 64;
    for (int idx = tid; idx < 4096; idx += 256) {
      int kk = idx >> 6, o = idx & 63;                    // coalesced over o
      SH[o * SSTR + kk] = Wv[(size_t)(k0 + kk) * DD + o];
    }
    __syncthreads();
    for (int idx = tid; idx < 4096; idx += 256) {
      int o = idx >> 6, kk = idx & 63;                    // coalesced over kk
      float wv = SH[o * SSTR + kk];
      unsigned short hi = f2bf(wv);
      WvTh[(size_t)o * 512 + k0 + kk] = hi;
      WvTl[(size_t)o * 512 + k0 + kk] = f2bf(wv - bf2f(hi));
    }
  }
}

// ---- Pass 2: hierarchical exclusive scan over 256 chunks, 4-way segmented ----
__global__ __launch_bounds__(576) void k_pass2(float* __restrict__ aggC,
                                               float* __restrict__ aggS) {
  const int bp = blockIdx.x;
  const int tid = threadIdx.x;
  __shared__ float totals[4][132];

  const bool act = tid < 520;
  int seg = 0, m = 0;
  float* base = aggC;
  int stride = 128;
  float vals[64];
  if (act) {
    seg = tid / 130;
    m = tid - seg * 130;
    if (m < 128) { base = aggC + (size_t)bp * NCH * 128 + m; stride = 128; }
    else         { base = aggS + (size_t)bp * NCH * 2 + (m - 128); stride = 2; }
    float run = 0.f;
#pragma unroll
    for (int u = 0; u < 64; ++u) vals[u] = base[(size_t)(seg * 64 + u) * stride];
#pragma unroll
    for (int u = 0; u < 64; ++u) run += vals[u];
    totals[seg][m] = run;
  }
  __syncthreads();
  if (act) {
    float r2 = 0.f;
    for (int s = 0; s < seg; ++s) r2 += totals[s][m];
#pragma unroll
    for (int u = 0; u < 64; ++u) {
      float v = vals[u];
      base[(size_t)(seg * 64 + u) * stride] = r2;
      r2 += v;
    }
  }
}

// ---- Pass 3: trig+scan -> Z(hi/lo bf16, swizzled) -> 3-term MFMA GEMM ----
__global__ __launch_bounds__(256, 4) void k_pass3(
    const float* __restrict__ q, const float* __restrict__ Wq,
    const float* __restrict__ Wk, const float* __restrict__ Wo,
    const float* __restrict__ aggC, const float* __restrict__ aggS,
    const unsigned short* __restrict__ WvTh,
    const unsigned short* __restrict__ WvTl,
    float* __restrict__ out) {
  const int blk = blockIdx.x;
  const int c = blk & (NCH - 1);
  const int b = blk >> 8;

  __shared__ float Qs[CC * 64];                           // 8 KB (cols only)
  __shared__ __align__(16) short Zbuf[2 * CC * 256];      // 32 KB: Zh | Zl

  const int tid = threadIdx.x;
  const int w = tid >> 6, l = tid & 63;
  const int lm = l & 15, lg = l >> 4;
  const int oc = w << 4;
  const int sub = l >> 5, tA = l & 31;
  const int pA = w + 4 * sub;

  // Prefetch h=0 B-fragments (WvT) into registers.
  short8 bhf[8], blf[8];
  {
    const unsigned short* ph_ = WvTh + (size_t)(oc + lm) * 512 + lg * 8;
    const unsigned short* pl_ = WvTl + (size_t)(oc + lm) * 512 + lg * 8;
#pragma unroll
    for (int kk = 0; kk < 8; ++kk) {
      bhf[kk] = *(const short8*)(ph_ + kk * 32);
      blf[kk] = *(const short8*)(pl_ + kk * 32);
    }
  }

  const float* qb = q + ((size_t)b * TT + (size_t)c * CC) * DD;
  for (int g = tid; g < CC * DD; g += 256) Qs[g] = qb[g];   // row-major, stride 64

  // Phase A: dots from GLOBAL rows (L1-hot) + trig + in-wave scan -> alpha/beta regs.
  float ckR, skR, alR, beR;
  {
    const float4* qr  = (const float4*)(qb + tA * DD);
    const float4* wqr = (const float4*)(Wq + pA * DD);
    const float4* wkr = (const float4*)(Wk + pA * DD);
    float dq = 0.f, dk = 0.f;
#pragma unroll
    for (int j = 0; j < 16; ++j) {
      float4 qv = qr[j], w0 = wqr[j], w1 = wkr[j];
      dq = fmaf(qv.x, w0.x, dq); dq = fmaf(qv.y, w0.y, dq);
      dq = fmaf(qv.z, w0.z, dq); dq = fmaf(qv.w, w0.w, dq);
      dk = fmaf(qv.x, w1.x, dk); dk = fmaf(qv.y, w1.y, dk);
      dk = fmaf(qv.z, w1.z, dk); dk = fmaf(qv.w, w1.w, dk);
    }
    float ang = fast_tanh(dq) * KPI4;
    float cq = __cosf(ang), sq = __sinf(ang);
    ang = fast_tanh(dk) * KPI4;
    ckR = __cosf(ang); skR = __sinf(ang);
    float rc = ckR, rs = skR;
#pragma unroll
    for (int d = 1; d < 32; d <<= 1) {
      float tc = __shfl_up(rc, (unsigned)d, 32);
      float ts = __shfl_up(rs, (unsigned)d, 32);
      if (tA >= d) { rc += tc; rs += ts; }
    }
    const float2 sgl = *(const float2*)(aggS + ((size_t)(b * PP + pA) * NCH + c) * 2);
    rc += sgl.x; rs += sgl.y;
    float den = fmaf(cq, rc, fmaf(sq, rs, EPSV));
    float ws = Wo[pA] * __builtin_amdgcn_rcpf(den);
    alR = ws * cq; beR = ws * sq;
  }

  // Prefetch scan-prefix state for both halves.
  const float* prC0 = aggC + ((size_t)(b * PP + w) * NCH + c) * 128;
  const float* prC1 = aggC + ((size_t)(b * PP + w + 4) * NCH + c) * 128;
  float Ac0 = prC0[l], As0 = prC0[64 + l];
  float Ac1 = prC1[l], As1 = prC1[64 + l];

  __syncthreads();

  // Q column into registers (conflict-free: lanes consecutive).
  float qcol[CC];
#pragma unroll
  for (int t = 0; t < CC; ++t) qcol[t] = Qs[t * 64 + l];

  // Swizzled write bases: k' = 64*w + l -> byte 128w+2l, XOR'd by (t&7)<<4.
  const int kb = (w << 7) + (l << 1);
  int xad[8];
#pragma unroll
  for (int r = 0; r < 8; ++r) xad[r] = kb ^ (r << 4);

  char* zbase = (char*)Zbuf;
  f32x4 acc0 = {0, 0, 0, 0}, acc1 = {0, 0, 0, 0};

  auto phaseC = [&]() {
#pragma unroll
    for (int kk = 0; kk < 8; ++kk) {
      const int sw = (kk * 64 + lg * 16) ^ ((lm & 7) << 4);
      const int rb0 = (lm << 9) + sw;
      const int rb1 = ((16 + lm) << 9) + sw;
      short8 ah0 = *(const short8*)(zbase + rb0);
      short8 al0 = *(const short8*)(zbase + 16384 + rb0);
      short8 ah1 = *(const short8*)(zbase + rb1);
      short8 al1 = *(const short8*)(zbase + 16384 + rb1);
      acc0 = __builtin_amdgcn_mfma_f32_16x16x32_bf16(ah0, bhf[kk], acc0, 0, 0, 0);
      acc1 = __builtin_amdgcn_mfma_f32_16x16x32_bf16(ah1, bhf[kk], acc1, 0, 0, 0);
      acc0 = __builtin_amdgcn_mfma_f32_16x16x32_bf16(al0, bhf[kk], acc0, 0, 0, 0);
      acc1 = __builtin_amdgcn_mfma_f32_16x16x32_bf16(al1, bhf[kk], acc1, 0, 0, 0);
      acc0 = __builtin_amdgcn_mfma_f32_16x16x32_bf16(ah0, blf[kk], acc0, 0, 0, 0);
      acc1 = __builtin_amdgcn_mfma_f32_16x16x32_bf16(ah1, blf[kk], acc1, 0, 0, 0);
    }
  };

  // ---- half 0: p = w, trig at lanes 0-31 ----
#pragma unroll
  for (int t = 0; t < CC; ++t) {
    float ck = rlane(ckR, t), sk = rlane(skR, t);
    float al = rlane(alR, t), be = rlane(beR, t);
    Ac0 = fmaf(ck, qcol[t], Ac0);
    As0 = fmaf(sk, qcol[t], As0);
    float z = fmaf(al, Ac0, be * As0);
    unsigned u = __float_as_uint(z);
    unsigned r = u + 0x7fffu + ((u >> 16) & 1u);
    float lo = z - __uint_as_float(r & 0xffff0000u);
    *(short*)(zbase + (t << 9) + xad[t & 7]) = (short)(r >> 16);
    *(short*)(zbase + 16384 + (t << 9) + xad[t & 7]) = (short)(__float_as_uint(lo) >> 16);
  }
  __syncthreads();
  phaseC();
  {  // prefetch h=1 B-fragments; hides under B(1)
    const unsigned short* ph_ = WvTh + (size_t)(oc + lm) * 512 + 256 + lg * 8;
    const unsigned short* pl_ = WvTl + (size_t)(oc + lm) * 512 + 256 + lg * 8;
#pragma unroll
    for (int kk = 0; kk < 8; ++kk) {
      bhf[kk] = *(const short8*)(ph_ + kk * 32);
      blf[kk] = *(const short8*)(pl_ + kk * 32);
    }
  }
  __syncthreads();

  // ---- half 1: p = w+4, trig at lanes 32-63 ----
#pragma unroll
  for (int t = 0; t < CC; ++t) {
    float ck = rlane(ckR, t + 32), sk = rlane(skR, t + 32);
    float al = rlane(alR, t + 32), be = rlane(beR, t + 32);
    Ac1 = fmaf(ck, qcol[t], Ac1);
    As1 = fmaf(sk, qcol[t], As1);
    float z = fmaf(al, Ac1, be * As1);
    unsigned u = __float_as_uint(z);
    unsigned r = u + 0x7fffu + ((u >> 16) & 1u);
    float lo = z - __uint_as_float(r & 0xffff0000u);
    *(short*)(zbase + (t << 9) + xad[t & 7]) = (short)(r >> 16);
    *(short*)(zbase + 16384 + (t << 9) + xad[t & 7]) = (short)(__float_as_uint(lo) >> 16);
  }
  __syncthreads();
  phaseC();

  // Epilogue: C/D layout col=lane&15 (o), row=(lane>>4)*4+reg (t)  [m89]
  {
    float* ob = out + ((size_t)b * TT + (size_t)c * CC + lg * 4) * DD + oc + lm;
#pragma unroll
    for (int r = 0; r < 4; ++r) {
      ob[r * DD] = acc0[r];
      ob[(16 + r) * DD] = acc1[r];
    }
  }
}

extern "C" void kernel_launch(void* const* d_in, const int* in_sizes, int n_in,
                              void* d_out, int out_size, void* d_ws, size_t ws_size,
                              hipStream_t stream) {
  const float* q  = (const float*)d_in[0];
  const float* Wq = (const float*)d_in[1];
  const float* Wk = (const float*)d_in[2];
  const float* Wv = (const float*)d_in[3];
  const float* Wo = (const float*)d_in[4];
  float* out = (float*)d_out;

  float* aggC = (float*)d_ws;                               // 4 MiB
  float* aggS = aggC + (size_t)BB * PP * NCH * 128;         // 64 KiB
  unsigned short* WvTh = (unsigned short*)(aggS + (size_t)BB * PP * NCH * 2);
  unsigned short* WvTl = WvTh + (size_t)512 * 64;           // 64 KiB each

  k_pass1<<<BB * NCH, 256, 0, stream>>>(q, Wk, Wv, aggC, aggS, WvTh, WvTl);
  k_pass2<<<BB * PP, 576, 0, stream>>>(aggC, aggS);
  k_pass3<<<BB * NCH, 256, 0, stream>>>(q, Wq, Wk, Wo, aggC, aggS, WvTh, WvTl, out);
}

// Round 6
// 56.612 us; speedup vs baseline: 1.1688x; 1.1688x over previous
//
#include <hip/hip_runtime.h>
#include <hip/hip_bf16.h>
#include <math.h>

#define BB  4
#define TT  8192
#define DD  64
#define PP  8
#define CC  32            // chunk length along t
#define NCH (TT/CC)       // 256 chunks
#define SSTR 65           // pass1 SH stride (floats): conflict-free rows+cols

#define EPSV 1e-3f
#define KPI4 0.78539816339744830962f

typedef __attribute__((ext_vector_type(8))) short short8;   // 8 bf16
typedef __attribute__((ext_vector_type(4))) float f32x4;

__device__ __forceinline__ float bf2f(unsigned short h) {
  return __uint_as_float(((unsigned)h) << 16);
}
__device__ __forceinline__ unsigned short f2bf(float f) {   // RNE
  unsigned u = __float_as_uint(f);
  u += 0x7fffu + ((u >> 16) & 1u);
  return (unsigned short)(u >> 16);
}
__device__ __forceinline__ float fast_tanh(float x) {
  float e = __expf(2.f * x);
  return 1.f - 2.f * __builtin_amdgcn_rcpf(e + 1.f);
}
__device__ __forceinline__ float rlane(float v, int lane) {
  return __uint_as_float(__builtin_amdgcn_readlane(__float_as_uint(v), lane));
}

// ---- Pass 1: per-(b,chunk) aggregates; blocks 0..7 also build WvT hi/lo ----
__global__ __launch_bounds__(256) void k_pass1(const float* __restrict__ q,
                                               const float* __restrict__ Wk,
                                               const float* __restrict__ Wv,
                                               float* __restrict__ aggC,
                                               float* __restrict__ aggS,
                                               unsigned short* __restrict__ WvTh,
                                               unsigned short* __restrict__ WvTl) {
  const int blk = blockIdx.x;
  const int c = blk & (NCH - 1);
  const int b = blk >> 8;

  __shared__ float SH[64 * SSTR];           // Q (32 rows used); reused for Wv

  const int tid = threadIdx.x;
  const int w = tid >> 6, l = tid & 63;
  const int sub = l >> 5, tA = l & 31;
  const int pA = w + 4 * sub;

  const float* qb = q + ((size_t)b * TT + (size_t)c * CC) * DD;
  for (int g = tid; g < CC * DD; g += 256) SH[(g >> 6) * SSTR + (g & 63)] = qb[g];

  // k-dot from GLOBAL (L1-hot) + trig; wave w holds p=w (lanes 0-31), p=w+4 (32-63)
  float ckR, skR;
  {
    const float4* qr = (const float4*)(qb + tA * DD);
    const float4* wr = (const float4*)(Wk + pA * DD);
    float dk = 0.f;
#pragma unroll
    for (int j = 0; j < 16; ++j) {
      float4 qv = qr[j], wv = wr[j];
      dk = fmaf(qv.x, wv.x, dk); dk = fmaf(qv.y, wv.y, dk);
      dk = fmaf(qv.z, wv.z, dk); dk = fmaf(qv.w, wv.w, dk);
    }
    float ang = fast_tanh(dk) * KPI4;
    ckR = __cosf(ang); skR = __sinf(ang);
    float rc = ckR, rs = skR;
#pragma unroll
    for (int d = 16; d >= 1; d >>= 1) {
      rc += __shfl_xor(rc, d, 32);
      rs += __shfl_xor(rs, d, 32);
    }
    if (tA == 0) {
      float* s = aggS + ((size_t)(b * PP + pA) * NCH + c) * 2;
      *(float2*)s = make_float2(rc, rs);
    }
  }
  __syncthreads();

  // d-space aggregates: wave w covers p=w and p=w+4; thread owns i=l.
  {
    float c0 = 0, s0 = 0, c1 = 0, s1 = 0;
#pragma unroll
    for (int t = 0; t < CC; ++t) {
      float qv = SH[t * SSTR + l];
      float a0 = rlane(ckR, t), b0 = rlane(skR, t);
      float a1 = rlane(ckR, t + 32), b1 = rlane(skR, t + 32);
      c0 = fmaf(a0, qv, c0); s0 = fmaf(b0, qv, s0);
      c1 = fmaf(a1, qv, c1); s1 = fmaf(b1, qv, s1);
    }
    float* a0p = aggC + ((size_t)(b * PP + w) * NCH + c) * 128;
    float* a1p = aggC + ((size_t)(b * PP + w + 4) * NCH + c) * 128;
    a0p[l] = c0; a0p[64 + l] = s0;
    a1p[l] = c1; a1p[64 + l] = s1;
  }

  // Wv transpose + double-bf16 split: blocks 0..7, one 64-k tile each.
  if (blk < 8) {
    __syncthreads();
    const int k0 = blk * 64;
    for (int idx = tid; idx < 4096; idx += 256) {
      int kk = idx >> 6, o = idx & 63;                    // coalesced over o
      SH[o * SSTR + kk] = Wv[(size_t)(k0 + kk) * DD + o];
    }
    __syncthreads();
    for (int idx = tid; idx < 4096; idx += 256) {
      int o = idx >> 6, kk = idx & 63;                    // coalesced over kk
      float wv = SH[o * SSTR + kk];
      unsigned short hi = f2bf(wv);
      WvTh[(size_t)o * 512 + k0 + kk] = hi;
      WvTl[(size_t)o * 512 + k0 + kk] = f2bf(wv - bf2f(hi));
    }
  }
}

// ---- Pass 2: hierarchical exclusive scan over 256 chunks, 4-way segmented ----
__global__ __launch_bounds__(576) void k_pass2(float* __restrict__ aggC,
                                               float* __restrict__ aggS) {
  const int bp = blockIdx.x;
  const int tid = threadIdx.x;
  __shared__ float totals[4][132];

  const bool act = tid < 520;
  int seg = 0, m = 0;
  float* base = aggC;
  int stride = 128;
  float vals[64];
  if (act) {
    seg = tid / 130;
    m = tid - seg * 130;
    if (m < 128) { base = aggC + (size_t)bp * NCH * 128 + m; stride = 128; }
    else         { base = aggS + (size_t)bp * NCH * 2 + (m - 128); stride = 2; }
    float run = 0.f;
#pragma unroll
    for (int u = 0; u < 64; ++u) vals[u] = base[(size_t)(seg * 64 + u) * stride];
#pragma unroll
    for (int u = 0; u < 64; ++u) run += vals[u];
    totals[seg][m] = run;
  }
  __syncthreads();
  if (act) {
    float r2 = 0.f;
    for (int s = 0; s < seg; ++s) r2 += totals[s][m];
#pragma unroll
    for (int u = 0; u < 64; ++u) {
      float v = vals[u];
      base[(size_t)(seg * 64 + u) * stride] = r2;
      r2 += v;
    }
  }
}

// ---- Pass 3: trig+scan -> Z(hi/lo bf16, swizzled) -> 3-term MFMA GEMM ----
__global__ __launch_bounds__(256, 4) void k_pass3(
    const float* __restrict__ q, const float* __restrict__ Wq,
    const float* __restrict__ Wk, const float* __restrict__ Wo,
    const float* __restrict__ aggC, const float* __restrict__ aggS,
    const unsigned short* __restrict__ WvTh,
    const unsigned short* __restrict__ WvTl,
    float* __restrict__ out) {
  const int blk = blockIdx.x;
  const int c = blk & (NCH - 1);
  const int b = blk >> 8;

  __shared__ float Qs[CC * 64];                           // 8 KB, row-major stride 64
  __shared__ __align__(16) short Zbuf[2 * CC * 256];      // 32 KB: Zh | Zl

  const int tid = threadIdx.x;
  const int w = tid >> 6, l = tid & 63;
  const int lm = l & 15, lg = l >> 4;
  const int oc = w << 4;
  const int sub = l >> 5, tA = l & 31;
  const int pA = w + 4 * sub;

  // Prefetch h=0 B-fragments (WvT) into registers.
  short8 bhf[8], blf[8];
  {
    const unsigned short* ph_ = WvTh + (size_t)(oc + lm) * 512 + lg * 8;
    const unsigned short* pl_ = WvTl + (size_t)(oc + lm) * 512 + lg * 8;
#pragma unroll
    for (int kk = 0; kk < 8; ++kk) {
      bhf[kk] = *(const short8*)(ph_ + kk * 32);
      blf[kk] = *(const short8*)(pl_ + kk * 32);
    }
  }

  const float* qb = q + ((size_t)b * TT + (size_t)c * CC) * DD;
  for (int g = tid; g < CC * DD; g += 256) Qs[g] = qb[g];

  // Phase A: dots from GLOBAL rows (L1-hot) + trig + in-wave scan -> alpha/beta regs.
  float ckR, skR, alR, beR;
  {
    const float4* qr  = (const float4*)(qb + tA * DD);
    const float4* wqr = (const float4*)(Wq + pA * DD);
    const float4* wkr = (const float4*)(Wk + pA * DD);
    float dq = 0.f, dk = 0.f;
#pragma unroll
    for (int j = 0; j < 16; ++j) {
      float4 qv = qr[j], w0 = wqr[j], w1 = wkr[j];
      dq = fmaf(qv.x, w0.x, dq); dq = fmaf(qv.y, w0.y, dq);
      dq = fmaf(qv.z, w0.z, dq); dq = fmaf(qv.w, w0.w, dq);
      dk = fmaf(qv.x, w1.x, dk); dk = fmaf(qv.y, w1.y, dk);
      dk = fmaf(qv.z, w1.z, dk); dk = fmaf(qv.w, w1.w, dk);
    }
    float ang = fast_tanh(dq) * KPI4;
    float cq = __cosf(ang), sq = __sinf(ang);
    ang = fast_tanh(dk) * KPI4;
    ckR = __cosf(ang); skR = __sinf(ang);
    float rc = ckR, rs = skR;
#pragma unroll
    for (int d = 1; d < 32; d <<= 1) {
      float tc = __shfl_up(rc, (unsigned)d, 32);
      float ts = __shfl_up(rs, (unsigned)d, 32);
      if (tA >= d) { rc += tc; rs += ts; }
    }
    const float2 sgl = *(const float2*)(aggS + ((size_t)(b * PP + pA) * NCH + c) * 2);
    rc += sgl.x; rs += sgl.y;
    float den = fmaf(cq, rc, fmaf(sq, rs, EPSV));
    float ws = Wo[pA] * __builtin_amdgcn_rcpf(den);
    alR = ws * cq; beR = ws * sq;
  }

  // Prefetch scan-prefix state for both halves.
  const float* prC0 = aggC + ((size_t)(b * PP + w) * NCH + c) * 128;
  const float* prC1 = aggC + ((size_t)(b * PP + w + 4) * NCH + c) * 128;
  float Ac0 = prC0[l], As0 = prC0[64 + l];
  float Ac1 = prC1[l], As1 = prC1[64 + l];

  __syncthreads();

  // Swizzled write bases: k' = 64*w + l -> byte 128w+2l, XOR'd by (t&7)<<4.
  const int kb = (w << 7) + (l << 1);
  int xad[8];
#pragma unroll
  for (int r = 0; r < 8; ++r) xad[r] = kb ^ (r << 4);

  char* zbase = (char*)Zbuf;
  f32x4 acc0 = {0, 0, 0, 0}, acc1 = {0, 0, 0, 0};

  auto phaseC = [&]() {
#pragma unroll
    for (int kk = 0; kk < 8; ++kk) {
      const int sw = (kk * 64 + lg * 16) ^ ((lm & 7) << 4);
      const int rb0 = (lm << 9) + sw;
      const int rb1 = ((16 + lm) << 9) + sw;
      short8 ah0 = *(const short8*)(zbase + rb0);
      short8 al0 = *(const short8*)(zbase + 16384 + rb0);
      short8 ah1 = *(const short8*)(zbase + rb1);
      short8 al1 = *(const short8*)(zbase + 16384 + rb1);
      acc0 = __builtin_amdgcn_mfma_f32_16x16x32_bf16(ah0, bhf[kk], acc0, 0, 0, 0);
      acc1 = __builtin_amdgcn_mfma_f32_16x16x32_bf16(ah1, bhf[kk], acc1, 0, 0, 0);
      acc0 = __builtin_amdgcn_mfma_f32_16x16x32_bf16(al0, bhf[kk], acc0, 0, 0, 0);
      acc1 = __builtin_amdgcn_mfma_f32_16x16x32_bf16(al1, bhf[kk], acc1, 0, 0, 0);
      acc0 = __builtin_amdgcn_mfma_f32_16x16x32_bf16(ah0, blf[kk], acc0, 0, 0, 0);
      acc1 = __builtin_amdgcn_mfma_f32_16x16x32_bf16(ah1, blf[kk], acc1, 0, 0, 0);
    }
  };

  // ---- half 0: p = w, trig at lanes 0-31 ----
#pragma unroll
  for (int t = 0; t < CC; ++t) {
    float qv = Qs[t * 64 + l];
    float ck = rlane(ckR, t), sk = rlane(skR, t);
    float al = rlane(alR, t), be = rlane(beR, t);
    Ac0 = fmaf(ck, qv, Ac0);
    As0 = fmaf(sk, qv, As0);
    float z = fmaf(al, Ac0, be * As0);
    unsigned u = __float_as_uint(z);
    unsigned r = u + 0x7fffu + ((u >> 16) & 1u);
    float lo = z - __uint_as_float(r & 0xffff0000u);
    *(short*)(zbase + (t << 9) + xad[t & 7]) = (short)(r >> 16);
    *(short*)(zbase + 16384 + (t << 9) + xad[t & 7]) = (short)(__float_as_uint(lo) >> 16);
  }
  __syncthreads();
  phaseC();
  {  // prefetch h=1 B-fragments; hides under B(1)
    const unsigned short* ph_ = WvTh + (size_t)(oc + lm) * 512 + 256 + lg * 8;
    const unsigned short* pl_ = WvTl + (size_t)(oc + lm) * 512 + 256 + lg * 8;
#pragma unroll
    for (int kk = 0; kk < 8; ++kk) {
      bhf[kk] = *(const short8*)(ph_ + kk * 32);
      blf[kk] = *(const short8*)(pl_ + kk * 32);
    }
  }
  __syncthreads();

  // ---- half 1: p = w+4, trig at lanes 32-63 ----
#pragma unroll
  for (int t = 0; t < CC; ++t) {
    float qv = Qs[t * 64 + l];
    float ck = rlane(ckR, t + 32), sk = rlane(skR, t + 32);
    float al = rlane(alR, t + 32), be = rlane(beR, t + 32);
    Ac1 = fmaf(ck, qv, Ac1);
    As1 = fmaf(sk, qv, As1);
    float z = fmaf(al, Ac1, be * As1);
    unsigned u = __float_as_uint(z);
    unsigned r = u + 0x7fffu + ((u >> 16) & 1u);
    float lo = z - __uint_as_float(r & 0xffff0000u);
    *(short*)(zbase + (t << 9) + xad[t & 7]) = (short)(r >> 16);
    *(short*)(zbase + 16384 + (t << 9) + xad[t & 7]) = (short)(__float_as_uint(lo) >> 16);
  }
  __syncthreads();
  phaseC();

  // Epilogue: C/D layout col=lane&15 (o), row=(lane>>4)*4+reg (t)  [m89]
  {
    float* ob = out + ((size_t)b * TT + (size_t)c * CC + lg * 4) * DD + oc + lm;
#pragma unroll
    for (int r = 0; r < 4; ++r) {
      ob[r * DD] = acc0[r];
      ob[(16 + r) * DD] = acc1[r];
    }
  }
}

extern "C" void kernel_launch(void* const* d_in, const int* in_sizes, int n_in,
                              void* d_out, int out_size, void* d_ws, size_t ws_size,
                              hipStream_t stream) {
  const float* q  = (const float*)d_in[0];
  const float* Wq = (const float*)d_in[1];
  const float* Wk = (const float*)d_in[2];
  const float* Wv = (const float*)d_in[3];
  const float* Wo = (const float*)d_in[4];
  float* out = (float*)d_out;

  float* aggC = (float*)d_ws;                               // 4 MiB
  float* aggS = aggC + (size_t)BB * PP * NCH * 128;         // 64 KiB
  unsigned short* WvTh = (unsigned short*)(aggS + (size_t)BB * PP * NCH * 2);
  unsigned short* WvTl = WvTh + (size_t)512 * 64;           // 64 KiB each

  k_pass1<<<BB * NCH, 256, 0, stream>>>(q, Wk, Wv, aggC, aggS, WvTh, WvTl);
  k_pass2<<<BB * PP, 576, 0, stream>>>(aggC, aggS);
  k_pass3<<<BB * NCH, 256, 0, stream>>>(q, Wq, Wk, Wo, aggC, aggS, WvTh, WvTl, out);
}

// Round 7
// 56.366 us; speedup vs baseline: 1.1739x; 1.0044x over previous
//
#include <hip/hip_runtime.h>
#include <hip/hip_bf16.h>
#include <math.h>

#define BB  4
#define TT  8192
#define DD  64
#define PP  8
#define CC  32            // chunk length along t
#define NCH (TT/CC)       // 256 chunks
#define SSTR 65           // pass2 WvT SH stride

#define EPSV 1e-3f
#define KPI4 0.78539816339744830962f

typedef __attribute__((ext_vector_type(8))) short short8;   // 8 bf16
typedef __attribute__((ext_vector_type(4))) float f32x4;

__device__ __forceinline__ float bf2f(unsigned short h) {
  return __uint_as_float(((unsigned)h) << 16);
}
__device__ __forceinline__ unsigned short f2bf(float f) {   // RNE
  unsigned u = __float_as_uint(f);
  u += 0x7fffu + ((u >> 16) & 1u);
  return (unsigned short)(u >> 16);
}
__device__ __forceinline__ float fast_tanh(float x) {
  float e = __expf(2.f * x);
  return 1.f - 2.f * __builtin_amdgcn_rcpf(e + 1.f);
}
__device__ __forceinline__ float rlane(float v, int lane) {
  return __uint_as_float(__builtin_amdgcn_readlane(__float_as_uint(v), lane));
}

// ---- Pass 1: all dots+trig+local-scan per (t,p); d-space aggregates. No LDS. ----
__global__ __launch_bounds__(256) void k_pass1(const float* __restrict__ q,
                                               const float* __restrict__ Wq,
                                               const float* __restrict__ Wk,
                                               float* __restrict__ aggC,
                                               float* __restrict__ aggS,
                                               float4* __restrict__ T4,
                                               float2* __restrict__ T2) {
  const int blk = blockIdx.x;
  const int c = blk & (NCH - 1);
  const int b = blk >> 8;

  const int tid = threadIdx.x;
  const int w = tid >> 6, l = tid & 63;
  const int sub = l >> 5, tA = l & 31;
  const int pA = w + 4 * sub;

  const float* qb = q + ((size_t)b * TT + (size_t)c * CC) * DD;

  // dots + trig; wave w holds p=w (lanes 0-31), p=w+4 (lanes 32-63)
  float ckR, skR;
  {
    const float4* qr  = (const float4*)(qb + tA * DD);
    const float4* wqr = (const float4*)(Wq + pA * DD);
    const float4* wkr = (const float4*)(Wk + pA * DD);
    float dq = 0.f, dk = 0.f;
#pragma unroll
    for (int j = 0; j < 16; ++j) {
      float4 qv = qr[j], w0 = wqr[j], w1 = wkr[j];
      dq = fmaf(qv.x, w0.x, dq); dq = fmaf(qv.y, w0.y, dq);
      dq = fmaf(qv.z, w0.z, dq); dq = fmaf(qv.w, w0.w, dq);
      dk = fmaf(qv.x, w1.x, dk); dk = fmaf(qv.y, w1.y, dk);
      dk = fmaf(qv.z, w1.z, dk); dk = fmaf(qv.w, w1.w, dk);
    }
    float ang = fast_tanh(dq) * KPI4;
    float cq = __cosf(ang), sq = __sinf(ang);
    ang = fast_tanh(dk) * KPI4;
    ckR = __cosf(ang); skR = __sinf(ang);

    // within-chunk inclusive scan of ck/sk (width-32 segments)
    float rc = ckR, rs = skR;
#pragma unroll
    for (int d = 1; d < 32; d <<= 1) {
      float tc = __shfl_up(rc, (unsigned)d, 32);
      float ts = __shfl_up(rs, (unsigned)d, 32);
      if (tA >= d) { rc += tc; rs += ts; }
    }
    const size_t idx = ((size_t)(b * NCH + c) * PP + pA) * 32 + tA;
    T4[idx] = make_float4(cq, sq, ckR, skR);
    T2[idx] = make_float2(rc, rs);
    if (tA == 31) {  // chunk total -> aggS (scanned across chunks by pass2)
      float* s = aggS + ((size_t)(b * PP + pA) * NCH + c) * 2;
      *(float2*)s = make_float2(rc, rs);
    }
  }

  // d-space aggregates: wave w covers p=w and p=w+4; thread owns i=l.
  {
    float c0 = 0, s0 = 0, c1 = 0, s1 = 0;
#pragma unroll
    for (int t = 0; t < CC; ++t) {
      float qv = qb[t * DD + l];          // coalesced row read, L1-hot
      float a0 = rlane(ckR, t), b0 = rlane(skR, t);
      float a1 = rlane(ckR, t + 32), b1 = rlane(skR, t + 32);
      c0 = fmaf(a0, qv, c0); s0 = fmaf(b0, qv, s0);
      c1 = fmaf(a1, qv, c1); s1 = fmaf(b1, qv, s1);
    }
    float* a0p = aggC + ((size_t)(b * PP + w) * NCH + c) * 128;
    float* a1p = aggC + ((size_t)(b * PP + w + 4) * NCH + c) * 128;
    a0p[l] = c0; a0p[64 + l] = s0;
    a1p[l] = c1; a1p[64 + l] = s1;
  }
}

// ---- Pass 2: chunk-level exclusive scan; blocks 0..7 also build WvT hi/lo ----
__global__ __launch_bounds__(576) void k_pass2(float* __restrict__ aggC,
                                               float* __restrict__ aggS,
                                               const float* __restrict__ Wv,
                                               unsigned short* __restrict__ WvTh,
                                               unsigned short* __restrict__ WvTl) {
  const int bp = blockIdx.x;
  const int tid = threadIdx.x;
  __shared__ float totals[4][132];
  __shared__ float SH[64 * SSTR];

  const bool act = tid < 520;
  int seg = 0, m = 0;
  float* base = aggC;
  int stride = 128;
  float vals[64];
  if (act) {
    seg = tid / 130;
    m = tid - seg * 130;
    if (m < 128) { base = aggC + (size_t)bp * NCH * 128 + m; stride = 128; }
    else         { base = aggS + (size_t)bp * NCH * 2 + (m - 128); stride = 2; }
    float run = 0.f;
#pragma unroll
    for (int u = 0; u < 64; ++u) vals[u] = base[(size_t)(seg * 64 + u) * stride];
#pragma unroll
    for (int u = 0; u < 64; ++u) run += vals[u];
    totals[seg][m] = run;
  }
  __syncthreads();
  if (act) {
    float r2 = 0.f;
    for (int s = 0; s < seg; ++s) r2 += totals[s][m];
#pragma unroll
    for (int u = 0; u < 64; ++u) {
      float v = vals[u];
      base[(size_t)(seg * 64 + u) * stride] = r2;
      r2 += v;
    }
  }

  // WvT build on blocks 0..7 (one 64-k tile each).
  if (bp < 8) {
    const int k0 = bp * 64;
    __syncthreads();
    for (int idx = tid; idx < 4096; idx += 576) {
      int kk = idx >> 6, o = idx & 63;                    // coalesced over o
      SH[o * SSTR + kk] = Wv[(size_t)(k0 + kk) * DD + o];
    }
    __syncthreads();
    for (int idx = tid; idx < 4096; idx += 576) {
      int o = idx >> 6, kk = idx & 63;                    // coalesced over kk
      float wv = SH[o * SSTR + kk];
      unsigned short hi = f2bf(wv);
      WvTh[(size_t)o * 512 + k0 + kk] = hi;
      WvTl[(size_t)o * 512 + k0 + kk] = f2bf(wv - bf2f(hi));
    }
  }
}

// ---- Pass 3: slim scan -> Z(hi/lo bf16, swizzled) -> 3-term MFMA GEMM ----
__global__ __launch_bounds__(256, 4) void k_pass3(
    const float* __restrict__ q, const float* __restrict__ Wo,
    const float* __restrict__ aggC, const float* __restrict__ aggS,
    const float4* __restrict__ T4, const float2* __restrict__ T2,
    const unsigned short* __restrict__ WvTh,
    const unsigned short* __restrict__ WvTl,
    float* __restrict__ out) {
  const int blk = blockIdx.x;
  const int c = blk & (NCH - 1);
  const int b = blk >> 8;

  __shared__ __align__(16) short Zbuf[2 * CC * 256];      // 32 KB: Zh | Zl
  __shared__ float4 trig4[PP][CC];                        // 4 KB {ck,sk,al,be}

  const int tid = threadIdx.x;
  const int w = tid >> 6, l = tid & 63;
  const int lm = l & 15, lg = l >> 4;
  const int oc = w << 4;
  const int sub = l >> 5, tA = l & 31;
  const int pA = w + 4 * sub;

  // Prefetch h=0 B-fragments (WvT) into registers.
  short8 bhf[8], blf[8];
  {
    const unsigned short* ph_ = WvTh + (size_t)(oc + lm) * 512 + lg * 8;
    const unsigned short* pl_ = WvTl + (size_t)(oc + lm) * 512 + lg * 8;
#pragma unroll
    for (int kk = 0; kk < 8; ++kk) {
      bhf[kk] = *(const short8*)(ph_ + kk * 32);
      blf[kk] = *(const short8*)(pl_ + kk * 32);
    }
  }

  const float* qb = q + ((size_t)b * TT + (size_t)c * CC) * DD;

  // Phase A (slim): load precomputed trig+local-scan, finish denom, stage to LDS.
  {
    const size_t idx = ((size_t)(b * NCH + c) * PP + pA) * 32 + tA;
    float4 tq = T4[idx];
    float2 tr = T2[idx];
    const float2 RC = *(const float2*)(aggS + ((size_t)(b * PP + pA) * NCH + c) * 2);
    float rc = tr.x + RC.x, rs = tr.y + RC.y;
    float den = fmaf(tq.x, rc, fmaf(tq.y, rs, EPSV));
    float ws = Wo[pA] * __builtin_amdgcn_rcpf(den);
    trig4[pA][tA] = make_float4(tq.z, tq.w, ws * tq.x, ws * tq.y);
    // same-wave produce/consume: no barrier needed (lgkmcnt ordering)
  }

  // Scan-prefix state for both halves.
  const float* prC0 = aggC + ((size_t)(b * PP + w) * NCH + c) * 128;
  const float* prC1 = aggC + ((size_t)(b * PP + w + 4) * NCH + c) * 128;
  float Ac0 = prC0[l], As0 = prC0[64 + l];
  float Ac1 = prC1[l], As1 = prC1[64 + l];

  // Swizzled write base: k' = 64*w + l -> byte 128w+2l, XOR'd by (t&7)<<4.
  const int kb = (w << 7) + (l << 1);
  char* zbase = (char*)Zbuf;
  f32x4 acc0 = {0, 0, 0, 0}, acc1 = {0, 0, 0, 0};

  auto phaseC = [&]() {
#pragma unroll
    for (int kk = 0; kk < 8; ++kk) {
      const int sw = (kk * 64 + lg * 16) ^ ((lm & 7) << 4);
      const int rb0 = (lm << 9) + sw;
      const int rb1 = ((16 + lm) << 9) + sw;
      short8 ah0 = *(const short8*)(zbase + rb0);
      short8 al0 = *(const short8*)(zbase + 16384 + rb0);
      short8 ah1 = *(const short8*)(zbase + rb1);
      short8 al1 = *(const short8*)(zbase + 16384 + rb1);
      acc0 = __builtin_amdgcn_mfma_f32_16x16x32_bf16(ah0, bhf[kk], acc0, 0, 0, 0);
      acc1 = __builtin_amdgcn_mfma_f32_16x16x32_bf16(ah1, bhf[kk], acc1, 0, 0, 0);
      acc0 = __builtin_amdgcn_mfma_f32_16x16x32_bf16(al0, bhf[kk], acc0, 0, 0, 0);
      acc1 = __builtin_amdgcn_mfma_f32_16x16x32_bf16(al1, bhf[kk], acc1, 0, 0, 0);
      acc0 = __builtin_amdgcn_mfma_f32_16x16x32_bf16(ah0, blf[kk], acc0, 0, 0, 0);
      acc1 = __builtin_amdgcn_mfma_f32_16x16x32_bf16(ah1, blf[kk], acc1, 0, 0, 0);
    }
  };

  // ---- half 0: p = w ----
#pragma unroll 8
  for (int t = 0; t < CC; ++t) {
    float qv = qb[t * DD + l];           // coalesced row read, L1-hot
    float4 v = trig4[w][t];              // b128 broadcast: {ck,sk,al,be}
    Ac0 = fmaf(v.x, qv, Ac0);
    As0 = fmaf(v.y, qv, As0);
    float z = fmaf(v.z, Ac0, v.w * As0);
    unsigned u = __float_as_uint(z);
    unsigned r = u + 0x7fffu + ((u >> 16) & 1u);
    float lo = z - __uint_as_float(r & 0xffff0000u);
    const int ad = (t << 9) + (kb ^ ((t & 7) << 4));
    *(short*)(zbase + ad) = (short)(r >> 16);
    *(short*)(zbase + 16384 + ad) = (short)(__float_as_uint(lo) >> 16);
  }
  __syncthreads();
  phaseC();
  {  // prefetch h=1 B-fragments
    const unsigned short* ph_ = WvTh + (size_t)(oc + lm) * 512 + 256 + lg * 8;
    const unsigned short* pl_ = WvTl + (size_t)(oc + lm) * 512 + 256 + lg * 8;
#pragma unroll
    for (int kk = 0; kk < 8; ++kk) {
      bhf[kk] = *(const short8*)(ph_ + kk * 32);
      blf[kk] = *(const short8*)(pl_ + kk * 32);
    }
  }
  __syncthreads();

  // ---- half 1: p = w+4 ----
#pragma unroll 8
  for (int t = 0; t < CC; ++t) {
    float qv = qb[t * DD + l];
    float4 v = trig4[w + 4][t];
    Ac1 = fmaf(v.x, qv, Ac1);
    As1 = fmaf(v.y, qv, As1);
    float z = fmaf(v.z, Ac1, v.w * As1);
    unsigned u = __float_as_uint(z);
    unsigned r = u + 0x7fffu + ((u >> 16) & 1u);
    float lo = z - __uint_as_float(r & 0xffff0000u);
    const int ad = (t << 9) + (kb ^ ((t & 7) << 4));
    *(short*)(zbase + ad) = (short)(r >> 16);
    *(short*)(zbase + 16384 + ad) = (short)(__float_as_uint(lo) >> 16);
  }
  __syncthreads();
  phaseC();

  // Epilogue: C/D layout col=lane&15 (o), row=(lane>>4)*4+reg (t)  [m89]
  {
    float* ob = out + ((size_t)b * TT + (size_t)c * CC + lg * 4) * DD + oc + lm;
#pragma unroll
    for (int r = 0; r < 4; ++r) {
      ob[r * DD] = acc0[r];
      ob[(16 + r) * DD] = acc1[r];
    }
  }
}

extern "C" void kernel_launch(void* const* d_in, const int* in_sizes, int n_in,
                              void* d_out, int out_size, void* d_ws, size_t ws_size,
                              hipStream_t stream) {
  const float* q  = (const float*)d_in[0];
  const float* Wq = (const float*)d_in[1];
  const float* Wk = (const float*)d_in[2];
  const float* Wv = (const float*)d_in[3];
  const float* Wo = (const float*)d_in[4];
  float* out = (float*)d_out;

  float* aggC = (float*)d_ws;                               // 4 MiB
  float* aggS = aggC + (size_t)BB * PP * NCH * 128;         // 64 KiB
  unsigned short* WvTh = (unsigned short*)(aggS + (size_t)BB * PP * NCH * 2);
  unsigned short* WvTl = WvTh + (size_t)512 * 64;           // 64 KiB each
  float4* T4 = (float4*)(WvTl + (size_t)512 * 64);          // 4 MiB
  float2* T2 = (float2*)(T4 + (size_t)BB * NCH * PP * 32);  // 2 MiB

  k_pass1<<<BB * NCH, 256, 0, stream>>>(q, Wq, Wk, aggC, aggS, T4, T2);
  k_pass2<<<BB * PP, 576, 0, stream>>>(aggC, aggS, Wv, WvTh, WvTl);
  k_pass3<<<BB * NCH, 256, 0, stream>>>(q, Wo, aggC, aggS, T4, T2, WvTh, WvTl, out);
}